// Round 11
// baseline (120.162 us; speedup 1.0000x reference)
//
#include <hip/hip_runtime.h>

#define B_    16
#define CIN_  128
#define COUT_ 128
#define N_    4096
#define K_    16

typedef __attribute__((ext_vector_type(8))) _Float16 f16x8;   // 8 f16 = 4 VGPR
typedef __attribute__((ext_vector_type(2))) _Float16 f16x2;   // arithmetic type
typedef __attribute__((ext_vector_type(2))) __fp16   h16x2;   // pkrtz ret type
typedef __attribute__((ext_vector_type(4))) float f32x4;
typedef __attribute__((ext_vector_type(4))) int   i32x4;

// v_cvt_pkrtz_f16_f32 returns __fp16x2; bitcast to the _Float16x2 we compute in
__device__ inline f16x2 pkrtz(float a, float b) {
  union { h16x2 r; f16x2 f; } u;
  u.r = __builtin_amdgcn_cvt_pkrtz(a, b);
  return u.f;
}
__device__ inline unsigned h2u(f16x2 h) {          // bitcast half2 -> u32
  union { f16x2 h; unsigned u; } x; x.h = h; return x.u;
}
__device__ inline f16x2 u2h(unsigned u) {          // bitcast u32 -> half2
  union { unsigned u; f16x2 h; } x; x.u = u; return x.h;
}
__device__ inline unsigned short f2h(float f) {    // 1x v_cvt_f16_f32 (RNE)
  _Float16 h = (_Float16)f;
  union { _Float16 h; unsigned short u; } x; x.h = h; return x.u;
}

// ---------------------------------------------------------------------------
// R11. gemm occupancy round -- the first that ACTUALLY raises waves/CU.
// R10 post-mortem: 2 blocks x 8 waves == R6's 1 block x 16 waves == 16
// waves/CU; latency hiding never changed (per-CU vs per-block units error).
// gemm's ~21us vs ~9us floor is latency-dominated (x: 32 strided loads/thread
// at L2/L3 latency; barrier-separated phases); VALU/store/conflict theories
// all falsified (R6/R7). FIX: 64n x 128co tile, 1024 blocks x 512 thr,
// LDS = Wl 34816 + He[64][148] 18944 = 53760 B -> 3 blocks/CU = 24 waves/CU
// (6/SIMD, +50%). launch_bounds(512,6): VGPR budget ~85 vs ~52 used, no
// spill. He pad 148: quad row-distance 4*74dw = 8 banks (mod 32) -> quads on
// +0/+8/+16/+24 -> the R7-diagnosed 8-way epilogue conflict becomes ~2-way
// (free) while KEEPING the 1KB coalesced h stores R7 lost.
// gemm block i covers aggr block i's exact 64n tile (same index formula,
// same XCD under round-robin) -> best-case L2 handoff.
// aggr: UNCHANGED (measured 17.1us = 84% of composed roofline).
// ---------------------------------------------------------------------------
// Kernel 1: h[b][n][co] = f16(relu(sum_ci W[co][ci]*x[b][ci][n]))
// 1024 blocks x 512 thr (3 blocks/CU); tile 64n x 128co; 8 waves =
// 4 n-slices x 2 co-halves.
// ---------------------------------------------------------------------------
__global__ __launch_bounds__(512, 6) void gemm_relu_k(
    const float* __restrict__ W, const float* __restrict__ x,
    unsigned short* __restrict__ h) {
  __shared__ unsigned short Wl[128 * 136];   // [co][ci] f16, +8 pad (34816 B)
  __shared__ unsigned short He[64 * 148];    // [n][co] f16, +20 pad (18944 B)
  const int tid  = threadIdx.x;
  const int l    = blockIdx.x;          // 0..1023
  const int slot = l >> 3;              // 0..127
  const int b    = ((l & 7) << 1) | (slot >> 6);
  const int n0   = (slot & 63) * 64;

  // ---- stage W fp32 -> f16 -> LDS: 4x v_cvt_pkrtz per 8 floats ----
#pragma unroll
  for (int r = 0; r < 4; ++r) {
    int id  = tid + 512 * r;    // 0..2047 segments of 8 floats
    int co  = id >> 4;          // 0..127
    int seg = id & 15;          // 8-elt segment along ci
    const float4* wp = reinterpret_cast<const float4*>(W + co * CIN_ + 8 * seg);
    float4 v0 = wp[0];
    float4 v1 = wp[1];
    f16x2 q0 = pkrtz(v0.x, v0.y);
    f16x2 q1 = pkrtz(v0.z, v0.w);
    f16x2 q2 = pkrtz(v1.x, v1.y);
    f16x2 q3 = pkrtz(v1.z, v1.w);
    *reinterpret_cast<uint4*>(&Wl[co * 136 + 8 * seg]) =
        make_uint4(h2u(q0), h2u(q1), h2u(q2), h2u(q3));
  }

  const int lane = tid & 63;
  const int w    = tid >> 6;    // wave 0..7
  const int wn   = w & 3;       // n slice [n0+16*wn, +16)
  const int wg   = w >> 2;      // co half [64*wg, +64)
  const int m    = lane & 15;
  const int quad = lane >> 4;

  // ---- A-fragments straight from global (overlap the W staging above);
  //      packed f16 conversion: 4x pkrtz per 8 loads ----
  const float* xb = x + (size_t)b * CIN_ * N_ + n0 + 16 * wn + m;
  f16x8 a[4];
#pragma unroll
  for (int s = 0; s < 4; ++s)
#pragma unroll
    for (int jj = 0; jj < 4; ++jj) {
      float e0 = xb[(size_t)(32 * s + 8 * quad + 2 * jj)     * N_];
      float e1 = xb[(size_t)(32 * s + 8 * quad + 2 * jj + 1) * N_];
      f16x2 p = pkrtz(e0, e1);
      a[s][2 * jj]     = p[0];
      a[s][2 * jj + 1] = p[1];
    }

  __syncthreads();

  const int nrow = 16 * wn + 4 * quad;   // block-local n of c[0] (0..63)
#pragma unroll
  for (int t = 0; t < 4; ++t) {   // 4 co-tiles of 16 within this wave's half
    f32x4 c = {0.f, 0.f, 0.f, 0.f};
#pragma unroll
    for (int s = 0; s < 4; ++s) { // K = 4 x 32
      f16x8 bf = *reinterpret_cast<const f16x8*>(
          &Wl[(64 * wg + 16 * t + m) * 136 + 32 * s + 8 * quad]);
      c = __builtin_amdgcn_mfma_f32_16x16x32_f16(a[s], bf, c, 0, 0, 0);
    }
    int co = 64 * wg + 16 * t + m;
#pragma unroll
    for (int r = 0; r < 4; ++r) {
      float v = c[r] > 0.f ? c[r] : 0.f;  // ReLU
      He[(nrow + r) * 148 + co] = f2h(v);  // pad 148: quads on distinct banks
    }
  }
  __syncthreads();

  // ---- vectorized store: 2 x dwordx4/thread, 1 KB contiguous per wave ----
  unsigned short* hb = h + ((size_t)b * N_ + n0) * COUT_;
  const int seg = tid & 15;
  const int nr  = tid >> 4;   // 0..31
#pragma unroll
  for (int p = 0; p < 2; ++p) {
    int n = nr + 32 * p;
    uint4 v = *reinterpret_cast<const uint4*>(&He[n * 148 + 8 * seg]);
    *reinterpret_cast<uint4*>(hb + (size_t)n * COUT_ + 8 * seg) = v;
  }
}

// ---------------------------------------------------------------------------
// Kernel 2: out[b][co][n] = (sum_{17} h[b][idx'][:])/17 + bias, idx' incl self
// UNCHANGED (measured 17.1us, 84% of composed roofline).
// 1024 blocks x 256 thr; 64n x 128co tile; q=tid&15 -> 8 co, g=tid>>4 -> 4 n;
// unroll-2 over k; packed f16 accumulate (v_pk_add_f16).
// ---------------------------------------------------------------------------
__global__ __launch_bounds__(256, 4) void aggr_k(
    const unsigned short* __restrict__ h, const int* __restrict__ ei,
    const float* __restrict__ bias, float* __restrict__ out) {
  __shared__ int idx_t[17 * 64];  // [k][n], k=16 is the self loop
  const int tid  = threadIdx.x;
  const int l    = blockIdx.x;
  const int rest = l >> 3;                        // 0..127
  const int b    = ((l & 7) << 1) | (rest >> 6);
  const int n0   = (rest & 63) * 64;

  {  // stage+transpose neighbor indices (coalesced int4, NT to spare L2)
    int n  = tid >> 2;       // 0..63
    int kq = tid & 3;        // int4 along k
    i32x4 v = __builtin_nontemporal_load(
        reinterpret_cast<const i32x4*>(ei + ((size_t)b * N_ + n0 + n) * K_) + kq);
    idx_t[(4 * kq + 0) * 64 + n] = v.x;
    idx_t[(4 * kq + 1) * 64 + n] = v.y;
    idx_t[(4 * kq + 2) * 64 + n] = v.z;
    idx_t[(4 * kq + 3) * 64 + n] = v.w;
    if (tid < 64) idx_t[16 * 64 + tid] = n0 + tid;  // self loop
  }
  __syncthreads();

  const int q = tid & 15;   // co = 8q..8q+7
  const int g = tid >> 4;   // n_local = 4g .. 4g+3
  const unsigned short* hb = h + (size_t)b * N_ * COUT_;

  // packed f16 accumulators: [n_local][dword pair of co]; f16 safe: terms
  // non-negative, sums <~20, ulp(20)=0.016 -> ~0.002 err after /17.
  f16x2 acc2[4][4];
#pragma unroll
  for (int j = 0; j < 4; ++j)
#pragma unroll
    for (int d = 0; d < 4; ++d) acc2[j][d] = (f16x2)(_Float16)0;

#pragma unroll 2
  for (int k = 0; k < 17; ++k) {
    uint4 v[4];
#pragma unroll
    for (int j = 0; j < 4; ++j) {
      int node = idx_t[k * 64 + 4 * g + j];
      v[j] = *reinterpret_cast<const uint4*>(hb + (size_t)node * COUT_ + 8 * q);
    }
#pragma unroll
    for (int j = 0; j < 4; ++j) {   // 4x v_pk_add_f16 per uint4
      acc2[j][0] += u2h(v[j].x);
      acc2[j][1] += u2h(v[j].y);
      acc2[j][2] += u2h(v[j].z);
      acc2[j][3] += u2h(v[j].w);
    }
  }

  const float norm = 1.0f / 17.0f;
  const float4 bv0 = *reinterpret_cast<const float4*>(bias + 8 * q);
  const float4 bv1 = *reinterpret_cast<const float4*>(bias + 8 * q + 4);
  float* ob = out + (size_t)b * COUT_ * N_ + n0 + 4 * g;
#pragma unroll
  for (int c = 0; c < 8; ++c) {
    int co = 8 * q + c;
    float bb = (c < 4) ? ((c == 0) ? bv0.x : (c == 1) ? bv0.y : (c == 2) ? bv0.z : bv0.w)
                       : ((c == 4) ? bv1.x : (c == 5) ? bv1.y : (c == 6) ? bv1.z : bv1.w);
    float4 r;
    r.x = (float)acc2[0][c >> 1][c & 1] * norm + bb;
    r.y = (float)acc2[1][c >> 1][c & 1] * norm + bb;
    r.z = (float)acc2[2][c >> 1][c & 1] * norm + bb;
    r.w = (float)acc2[3][c >> 1][c & 1] * norm + bb;
    *reinterpret_cast<float4*>(ob + (size_t)co * N_) = r;  // 16B, 64B/segment
  }
}

extern "C" void kernel_launch(void* const* d_in, const int* in_sizes, int n_in,
                              void* d_out, int out_size, void* d_ws, size_t ws_size,
                              hipStream_t stream) {
  const float* x    = (const float*)d_in[0];
  const int*   ei   = (const int*)d_in[1];   // [2][B][N][K]; plane 0
  const float* W    = (const float*)d_in[2];
  const float* bias = (const float*)d_in[3];
  float* out = (float*)d_out;
  unsigned short* h = (unsigned short*)d_ws;  // 16 MB (f16)

  gemm_relu_k<<<dim3(1024), dim3(512), 0, stream>>>(W, x, h);
  aggr_k<<<dim3(B_ * N_ / 64), 256, 0, stream>>>(h, ei, bias, out);
}

// Round 12
// 113.429 us; speedup vs baseline: 1.0594x; 1.0594x over previous
//
#include <hip/hip_runtime.h>

#define B_    16
#define CIN_  128
#define COUT_ 128
#define N_    4096
#define K_    16

typedef __attribute__((ext_vector_type(8))) _Float16 f16x8;   // 8 f16 = 4 VGPR
typedef __attribute__((ext_vector_type(2))) _Float16 f16x2;   // arithmetic type
typedef __attribute__((ext_vector_type(2))) __fp16   h16x2;   // pkrtz ret type
typedef __attribute__((ext_vector_type(4))) float f32x4;
typedef __attribute__((ext_vector_type(4))) int   i32x4;

// v_cvt_pkrtz_f16_f32 returns __fp16x2; bitcast to the _Float16x2 we compute in
__device__ inline f16x2 pkrtz(float a, float b) {
  union { h16x2 r; f16x2 f; } u;
  u.r = __builtin_amdgcn_cvt_pkrtz(a, b);
  return u.f;
}
__device__ inline unsigned h2u(f16x2 h) {          // bitcast half2 -> u32
  union { f16x2 h; unsigned u; } x; x.h = h; return x.u;
}
__device__ inline f16x2 u2h(unsigned u) {          // bitcast u32 -> half2
  union { unsigned u; f16x2 h; } x; x.u = u; return x.h;
}
__device__ inline unsigned short f2h(float f) {    // 1x v_cvt_f16_f32 (RNE)
  _Float16 h = (_Float16)f;
  union { _Float16 h; unsigned short u; } x; x.h = h; return x.u;
}

// ---------------------------------------------------------------------------
// R12. The last untried gemm quadrant: KEEP the 256n tile (W staged by only
// 256 blocks -- R11 proved staging amortization dominates) AND raise
// occupancy to 32 waves/CU. How: halve He to [128][144] (LDS 108.5->71.7KB
// => 2 blocks x 16 waves co-resident; threads 2048 = cap) and run the
// MFMA+transpose epilogue in TWO half-tile passes (waves 0-7 compute n-local
// 0..127, all waves store; then waves 8-15 compute 128..255, store). The
// latency-dominated x-load phase stays fully parallel across 16 waves; the
// half-idle MFMA passes (~1us of MFMA total) are covered by the co-resident
// block. launch_bounds(1024,8): 64-VGPR cap vs ~52 measured demand for this
// body (R1) -- no R2-style collapse expected (that came from phase-2 arrays).
// Ledger: VALU-bound falsified (R6); store coalescing must keep He (R7);
// block-split at const waves neutral (R10); small-tile occupancy regresses
// via staging (R11).
// aggr: UNCHANGED (measured 17.1us = 84% of composed roofline).
// ---------------------------------------------------------------------------
// Kernel 1: h[b][n][co] = f16(relu(sum_ci W[co][ci]*x[b][ci][n]))
// 256 blocks x 1024 thr (2 blocks/CU, 32 waves/CU); tile 256n x 128co.
// ---------------------------------------------------------------------------
__global__ __launch_bounds__(1024, 8) void gemm_relu_k(
    const float* __restrict__ W, const float* __restrict__ x,
    unsigned short* __restrict__ h) {
  __shared__ unsigned short Wl[128 * 136];   // [co][ci] f16, +8 pad (34816 B)
  __shared__ unsigned short He[128 * 144];   // [n][co] f16, +16 pad (36864 B)
  const int tid  = threadIdx.x;
  const int l    = blockIdx.x;          // 0..255
  const int slot = l >> 3;              // 0..31
  const int b    = ((l & 7) << 1) | (slot >> 4);
  const int n0   = (slot & 15) * 256;

  // ---- stage W fp32 -> f16 -> LDS: 4x v_cvt_pkrtz per 8 floats ----
#pragma unroll
  for (int r = 0; r < 2; ++r) {
    int id  = tid + 1024 * r;   // 0..2047 segments of 8 floats
    int co  = id >> 4;          // 0..127
    int seg = id & 15;          // 8-elt segment along ci
    const float4* wp = reinterpret_cast<const float4*>(W + co * CIN_ + 8 * seg);
    float4 v0 = wp[0];
    float4 v1 = wp[1];
    f16x2 q0 = pkrtz(v0.x, v0.y);
    f16x2 q1 = pkrtz(v0.z, v0.w);
    f16x2 q2 = pkrtz(v1.x, v1.y);
    f16x2 q3 = pkrtz(v1.z, v1.w);
    *reinterpret_cast<uint4*>(&Wl[co * 136 + 8 * seg]) =
        make_uint4(h2u(q0), h2u(q1), h2u(q2), h2u(q3));
  }

  const int lane = tid & 63;
  const int w    = tid >> 6;    // wave 0..15 -> n slice [n0+16w, +16)
  const int m    = lane & 15;
  const int quad = lane >> 4;

  // ---- A-fragments straight from global (overlap the W staging above);
  //      all 16 waves load in parallel -- the latency-dominated phase ----
  const float* xb = x + (size_t)b * CIN_ * N_ + n0 + 16 * w + m;
  f16x8 a[4];
#pragma unroll
  for (int s = 0; s < 4; ++s)
#pragma unroll
    for (int jj = 0; jj < 4; ++jj) {
      float e0 = xb[(size_t)(32 * s + 8 * quad + 2 * jj)     * N_];
      float e1 = xb[(size_t)(32 * s + 8 * quad + 2 * jj + 1) * N_];
      f16x2 p = pkrtz(e0, e1);
      a[s][2 * jj]     = p[0];
      a[s][2 * jj + 1] = p[1];
    }

  __syncthreads();

  // ---- two half-tile epilogue passes through the halved He buffer ----
  const int wh   = w & 7;                 // wave index within its half
  const int nrow = 16 * wh + 4 * quad;    // He-local row of c[0] (0..127)
  unsigned short* hb = h + ((size_t)b * N_ + n0) * COUT_;
  const int seg = tid & 15;
  const int nr  = tid >> 4;   // 0..63
#pragma unroll
  for (int half = 0; half < 2; ++half) {
    if ((w >> 3) == half) {   // wave-uniform branch
#pragma unroll
      for (int t = 0; t < 8; ++t) {   // 8 co-tiles of 16
        f32x4 c = {0.f, 0.f, 0.f, 0.f};
#pragma unroll
        for (int s = 0; s < 4; ++s) { // K = 4 x 32
          f16x8 bf = *reinterpret_cast<const f16x8*>(
              &Wl[(16 * t + m) * 136 + 32 * s + 8 * quad]);
          c = __builtin_amdgcn_mfma_f32_16x16x32_f16(a[s], bf, c, 0, 0, 0);
        }
        int co = 16 * t + m;
#pragma unroll
        for (int r = 0; r < 4; ++r) {
          float v = c[r] > 0.f ? c[r] : 0.f;  // ReLU
          He[(nrow + r) * 144 + co] = f2h(v);
        }
      }
    }
    __syncthreads();   // half's He complete
    // store 128 rows: 1024 thr x 2 dwordx4, 1 KB contiguous per wave
#pragma unroll
    for (int p = 0; p < 2; ++p) {
      int n = nr + 64 * p;   // He-local 0..127
      uint4 v = *reinterpret_cast<const uint4*>(&He[n * 144 + 8 * seg]);
      *reinterpret_cast<uint4*>(hb + (size_t)(128 * half + n) * COUT_ + 8 * seg) = v;
    }
    __syncthreads();   // He free for the next half's writers
  }
}

// ---------------------------------------------------------------------------
// Kernel 2: out[b][co][n] = (sum_{17} h[b][idx'][:])/17 + bias, idx' incl self
// UNCHANGED (measured 17.1us, 84% of composed roofline).
// 1024 blocks x 256 thr; 64n x 128co tile; q=tid&15 -> 8 co, g=tid>>4 -> 4 n;
// unroll-2 over k; packed f16 accumulate (v_pk_add_f16).
// ---------------------------------------------------------------------------
__global__ __launch_bounds__(256, 4) void aggr_k(
    const unsigned short* __restrict__ h, const int* __restrict__ ei,
    const float* __restrict__ bias, float* __restrict__ out) {
  __shared__ int idx_t[17 * 64];  // [k][n], k=16 is the self loop
  const int tid  = threadIdx.x;
  const int l    = blockIdx.x;
  const int rest = l >> 3;                        // 0..127
  const int b    = ((l & 7) << 1) | (rest >> 6);
  const int n0   = (rest & 63) * 64;

  {  // stage+transpose neighbor indices (coalesced int4, NT to spare L2)
    int n  = tid >> 2;       // 0..63
    int kq = tid & 3;        // int4 along k
    i32x4 v = __builtin_nontemporal_load(
        reinterpret_cast<const i32x4*>(ei + ((size_t)b * N_ + n0 + n) * K_) + kq);
    idx_t[(4 * kq + 0) * 64 + n] = v.x;
    idx_t[(4 * kq + 1) * 64 + n] = v.y;
    idx_t[(4 * kq + 2) * 64 + n] = v.z;
    idx_t[(4 * kq + 3) * 64 + n] = v.w;
    if (tid < 64) idx_t[16 * 64 + tid] = n0 + tid;  // self loop
  }
  __syncthreads();

  const int q = tid & 15;   // co = 8q..8q+7
  const int g = tid >> 4;   // n_local = 4g .. 4g+3
  const unsigned short* hb = h + (size_t)b * N_ * COUT_;

  // packed f16 accumulators: [n_local][dword pair of co]; f16 safe: terms
  // non-negative, sums <~20, ulp(20)=0.016 -> ~0.002 err after /17.
  f16x2 acc2[4][4];
#pragma unroll
  for (int j = 0; j < 4; ++j)
#pragma unroll
    for (int d = 0; d < 4; ++d) acc2[j][d] = (f16x2)(_Float16)0;

#pragma unroll 2
  for (int k = 0; k < 17; ++k) {
    uint4 v[4];
#pragma unroll
    for (int j = 0; j < 4; ++j) {
      int node = idx_t[k * 64 + 4 * g + j];
      v[j] = *reinterpret_cast<const uint4*>(hb + (size_t)node * COUT_ + 8 * q);
    }
#pragma unroll
    for (int j = 0; j < 4; ++j) {   // 4x v_pk_add_f16 per uint4
      acc2[j][0] += u2h(v[j].x);
      acc2[j][1] += u2h(v[j].y);
      acc2[j][2] += u2h(v[j].z);
      acc2[j][3] += u2h(v[j].w);
    }
  }

  const float norm = 1.0f / 17.0f;
  const float4 bv0 = *reinterpret_cast<const float4*>(bias + 8 * q);
  const float4 bv1 = *reinterpret_cast<const float4*>(bias + 8 * q + 4);
  float* ob = out + (size_t)b * COUT_ * N_ + n0 + 4 * g;
#pragma unroll
  for (int c = 0; c < 8; ++c) {
    int co = 8 * q + c;
    float bb = (c < 4) ? ((c == 0) ? bv0.x : (c == 1) ? bv0.y : (c == 2) ? bv0.z : bv0.w)
                       : ((c == 4) ? bv1.x : (c == 5) ? bv1.y : (c == 6) ? bv1.z : bv1.w);
    float4 r;
    r.x = (float)acc2[0][c >> 1][c & 1] * norm + bb;
    r.y = (float)acc2[1][c >> 1][c & 1] * norm + bb;
    r.z = (float)acc2[2][c >> 1][c & 1] * norm + bb;
    r.w = (float)acc2[3][c >> 1][c & 1] * norm + bb;
    *reinterpret_cast<float4*>(ob + (size_t)co * N_) = r;  // 16B, 64B/segment
  }
}

extern "C" void kernel_launch(void* const* d_in, const int* in_sizes, int n_in,
                              void* d_out, int out_size, void* d_ws, size_t ws_size,
                              hipStream_t stream) {
  const float* x    = (const float*)d_in[0];
  const int*   ei   = (const int*)d_in[1];   // [2][B][N][K]; plane 0
  const float* W    = (const float*)d_in[2];
  const float* bias = (const float*)d_in[3];
  float* out = (float*)d_out;
  unsigned short* h = (unsigned short*)d_ws;  // 16 MB (f16)

  gemm_relu_k<<<dim3(256), dim3(1024), 0, stream>>>(W, x, h);
  aggr_k<<<dim3(B_ * N_ / 64), 256, 0, stream>>>(h, ei, bias, out);
}